// Round 1
// 69.054 us; speedup vs baseline: 1.0398x; 1.0398x over previous
//
#include <hip/hip_runtime.h>
#include <math.h>

// Tropical (max-plus) 3x3 conv:
// out[b,o,y,x] = max_{c,dy,dx} imgs[b,c,y+dy-1,x+dx-1] + kernel[o,c,2-dy,2-dx]
// B=8, C=32, O=32, H=W=32, PADDING=1 (-inf), fp32.
//
// R5 design (occupancy experiment):
//  - R4 ran 1024 waves over 1024 SIMDs = 1 wave/SIMD -> every vmcnt/lgkm
//    stall fully exposed (kernel ~15x above its ~2us VALU floor; R1->R4
//    fixes moved total by only 0.2us because another latency source just
//    took over).
//  - R5: each lane does 1 output row x 1 output channel. Grid = b(8) x
//    o(32) x y-quarter(4) = 1024 blocks of 256 threads -> 4096 waves =
//    4 waves/SIMD. 4x latency hiding, per-wave work 4x smaller.
//  - Everything else keeps the R4-verified structure: coalesced row loads,
//    UNCONDITIONAL shuffles then edge-mask (convergence bug fix retained),
//    uniform ds_read_b128 weight broadcast from 16-float-padded LDS,
//    no s_load in the hot loop.

constexpr int B = 8, C = 32, O = 32, H = 32, W = 32;

__device__ __forceinline__ float f3(float a, float b, float c) {
  return fmaxf(fmaxf(a, b), c);  // -> v_max3_f32
}

__global__ __launch_bounds__(256, 4) void trop_conv_kernel(
    const float* __restrict__ img, const float* __restrict__ kern,
    float* __restrict__ out) {
  __shared__ float sw[32 * 16];  // [c][16], taps 0..8 valid

  const int tid = threadIdx.x;
  const int blk = blockIdx.x;
  const int yq = blk & 3;           // quarter of rows (8 rows)
  const int o = (blk >> 2) & 31;    // output channel
  const int b = blk >> 7;

  // ---- stage this o's 288 weights into padded LDS ----
  const float* kw = kern + o * 288;
  for (int j = tid; j < 288; j += 256) {
    int c = j / 9;
    int t = j - c * 9;
    sw[c * 16 + t] = kw[j];
  }
  __syncthreads();

  const int x = tid & 31;
  const int r = tid >> 5;           // 0..7
  const int y = yq * 8 + r;         // this lane's single output row

  // per-lane clamped row offsets (floats), loop-invariant
  int ro0, ro1, ro2;
  {
    int ym = y - 1; ym = ym < 0 ? 0 : ym;
    int yp = y + 1; yp = yp > 31 ? 31 : yp;
    ro0 = ym * W + x;
    ro1 = y * W + x;
    ro2 = yp * W + x;
  }
  const bool top_oob = (y == 0);
  const bool bot_oob = (y == 31);
  const bool xz = (x == 0);
  const bool xe = (x == 31);
  const float NEG = -__builtin_huge_valf();

  const float* ib = img + b * C * H * W;

  float acc = NEG;

#pragma unroll 8
  for (int c = 0; c < C; ++c) {
    const float* ic = ib + c * H * W;
    float v0 = ic[ro0];
    float v1 = ic[ro1];
    float v2 = ic[ro2];
    v0 = top_oob ? NEG : v0;
    v2 = bot_oob ? NEG : v2;

    // Cross-lane shifts: UNCONDITIONAL (all 64 lanes active — convergent op
    // must not sit inside a ternary/branch), THEN mask the edge lanes.
    // Wave holds 2 y-rows (lanes 0..31 = row r, 32..63 = row r+1); the
    // cross-row leak at lane 32/31 is exactly the x==0 / x==31 case and is
    // masked to NEG below.
    float l0 = __shfl_up(v0, 1), r0 = __shfl_down(v0, 1);
    float l1 = __shfl_up(v1, 1), r1 = __shfl_down(v1, 1);
    float l2 = __shfl_up(v2, 1), r2 = __shfl_down(v2, 1);
    l0 = xz ? NEG : l0;  r0 = xe ? NEG : r0;
    l1 = xz ? NEG : l1;  r1 = xe ? NEG : r1;
    l2 = xz ? NEG : l2;  r2 = xe ? NEG : r2;

    // uniform (broadcast) weight reads; slots s0..s8, s = 8 - (3*dy + dx)
    const float4 A0 = *(const float4*)&sw[c * 16];
    const float4 A1 = *(const float4*)&sw[c * 16 + 4];
    const float A8 = sw[c * 16 + 8];

    // rows (y-1, y, y+1) = (v0, v1, v2); dx: L/C/R; weight slot 8-3dy-dx
    float t0 = f3(l0 + A8,   v0 + A1.w, r0 + A1.z);
    float t1 = f3(l1 + A1.y, v1 + A1.x, r1 + A0.w);
    float t2 = f3(l2 + A0.z, v2 + A0.y, r2 + A0.x);
    acc = fmaxf(acc, f3(t0, t1, t2));
  }

  out[((b * O + o) * H + y) * W + x] = acc;
}

extern "C" void kernel_launch(void* const* d_in, const int* in_sizes, int n_in,
                              void* d_out, int out_size, void* d_ws, size_t ws_size,
                              hipStream_t stream) {
  const float* img = (const float*)d_in[0];
  const float* kern = (const float*)d_in[1];
  float* out = (float*)d_out;
  // grid: b(8) x o(32) x y-quarter(4) = 1024 blocks of 256 threads
  //       -> 4096 waves = 4 waves/SIMD (vs R4's 1 wave/SIMD)
  trop_conv_kernel<<<dim3(1024), dim3(256), 0, stream>>>(img, kern, out);
}

// Round 2
// 63.575 us; speedup vs baseline: 1.1294x; 1.0862x over previous
//
#include <hip/hip_runtime.h>
#include <math.h>

// Tropical (max-plus) 3x3 conv:
// out[b,o,y,x] = max_{c,dy,dx} imgs[b,c,y+dy-1,x+dx-1] + kernel[o,c,2-dy,2-dx]
// B=8, C=32, O=32, H=W=32, PADDING=1 (-inf), fp32.
//
// R6 design (LDS-pipe elimination):
//  - Post-mortem of R5: 4x occupancy bought only 2.75us -> kernel is NOT
//    latency-bound; arithmetic says the per-CU LDS pipe (6 ds_bpermute
//    shuffles + 3 broadcast weight reads per wave-iter) is ~14us of the
//    ~25us kernel residual. So: remove ALL DS ops from the hot loop.
//  - Horizontal neighbors: each lane owns 2 consecutive x (x0 even).
//    One dwordx4 per row at clamped base xb = clamp(x0-1, 0, 28) covers
//    x0-1..x0+2; edge lanes remap via cndmask and inject -inf. No
//    shuffles. Base clamp keeps every access inside the buffer (last
//    read ends exactly at the final element).
//  - Weights: direct loads from kern at wave-uniform addresses
//    (const __restrict__) -> clang promotes to s_load (SMEM). With zero
//    DS in the loop, lgkmcnt carries SMEM only -> R1's SMEM+DS
//    serialization hazard cannot occur. No LDS in the kernel at all.
//  - Grid: b(8) x o(32) x y-half(2) = 512 blocks x 256 thr = 2048 waves
//    = 2 waves/SIMD; unroll 4 keeps 12 loads in flight for L2 latency.

constexpr int B = 8, C = 32, O = 32, H = 32, W = 32;
constexpr int HW = H * W;

typedef float f4 __attribute__((ext_vector_type(4)));

__device__ __forceinline__ float f3(float a, float b, float c) {
  return fmaxf(fmaxf(a, b), c);  // -> v_max3_f32
}

// 16B load with only 4B alignment guaranteed (xb may be odd).
__device__ __forceinline__ f4 ld4u(const float* p) {
  f4 q;
  __builtin_memcpy(&q, p, sizeof(q));
  return q;
}

__global__ __launch_bounds__(256, 2) void trop_conv_kernel(
    const float* __restrict__ img, const float* __restrict__ kern,
    float* __restrict__ out) {
  const int tid = threadIdx.x;
  const int blk = blockIdx.x;
  const int yh = blk & 1;           // y-half (16 rows)
  const int o = (blk >> 1) & 31;    // output channel
  const int b = blk >> 6;

  const int seg = tid & 15;         // x-segment: 2 px per lane
  const int x0 = seg * 2;
  const int r = tid >> 4;           // 0..15
  const int y = yh * 16 + r;

  // clamped load base: q covers img columns xb..xb+3
  int xb = x0 - 1;
  xb = xb < 0 ? 0 : xb;
  xb = xb > 28 ? 28 : xb;
  int ym = y - 1; ym = ym < 0 ? 0 : ym;
  int yp = y + 1; yp = yp > 31 ? 31 : yp;
  const int off0 = ym * W + xb;
  const int off1 = y * W + xb;
  const int off2 = yp * W + xb;

  const bool top = (y == 0);
  const bool bot = (y == 31);
  const bool xz = (x0 == 0);    // xb == x0   -> q = x0..x0+3
  const bool xe = (x0 == 30);   // xb == x0-2 -> q = x0-2..x0+1
  const float NEG = -__builtin_huge_valf();

  const float* ib = img + b * C * HW;
  const float* kc = kern + o * 288;

  float acc0 = NEG, acc1 = NEG;

#pragma unroll 4
  for (int c = 0; c < C; ++c) {
    const float* ic = ib + c * HW;
    const float* kp = kc + c * 9;
    // wave-uniform weight loads (expect s_load); w[t] = kern[o][c][t/3][t%3]
    const float w0 = kp[0], w1 = kp[1], w2 = kp[2], w3 = kp[3], w4 = kp[4],
                w5 = kp[5], w6 = kp[6], w7 = kp[7], w8 = kp[8];

    const f4 q0 = ld4u(ic + off0);  // row y-1
    const f4 q1 = ld4u(ic + off1);  // row y
    const f4 q2 = ld4u(ic + off2);  // row y+1

    // remap to (x0-1, x0, x0+1, x0+2), edges -> NEG
    const float am = xz ? NEG : (xe ? q0.y : q0.x);
    const float a0 = xe ? q0.z : (xz ? q0.x : q0.y);
    const float a1 = xe ? q0.w : (xz ? q0.y : q0.z);
    const float a2 = xe ? NEG : (xz ? q0.z : q0.w);

    const float bm = xz ? NEG : (xe ? q1.y : q1.x);
    const float b0 = xe ? q1.z : (xz ? q1.x : q1.y);
    const float b1 = xe ? q1.w : (xz ? q1.y : q1.z);
    const float b2 = xe ? NEG : (xz ? q1.z : q1.w);

    const float cm = xz ? NEG : (xe ? q2.y : q2.x);
    const float c0 = xe ? q2.z : (xz ? q2.x : q2.y);
    const float c1 = xe ? q2.w : (xz ? q2.y : q2.z);
    const float c2 = xe ? NEG : (xz ? q2.z : q2.w);

    // weight slot s = 8 - 3*dy - dx; rows (y-1, y, y+1) = dy (0,1,2)
    float t0a = f3(am + w8, a0 + w7, a1 + w6);   // out x0,   row y-1
    float t1a = f3(a0 + w8, a1 + w7, a2 + w6);   // out x0+1, row y-1
    t0a = top ? NEG : t0a;
    t1a = top ? NEG : t1a;

    const float t0b = f3(bm + w5, b0 + w4, b1 + w3);  // row y
    const float t1b = f3(b0 + w5, b1 + w4, b2 + w3);

    float t0c = f3(cm + w2, c0 + w1, c1 + w0);   // row y+1
    float t1c = f3(c0 + w2, c1 + w1, c2 + w0);
    t0c = bot ? NEG : t0c;
    t1c = bot ? NEG : t1c;

    acc0 = fmaxf(acc0, f3(t0a, t0b, t0c));
    acc1 = fmaxf(acc1, f3(t1a, t1b, t1c));
  }

  // two consecutive outputs per lane; 8B-aligned (x0 even)
  float2 res = make_float2(acc0, acc1);
  *reinterpret_cast<float2*>(&out[((b * O + o) * H + y) * W + x0]) = res;
}

extern "C" void kernel_launch(void* const* d_in, const int* in_sizes, int n_in,
                              void* d_out, int out_size, void* d_ws, size_t ws_size,
                              hipStream_t stream) {
  const float* img = (const float*)d_in[0];
  const float* kern = (const float*)d_in[1];
  float* out = (float*)d_out;
  // grid: b(8) x o(32) x y-half(2) = 512 blocks of 256 threads
  //       -> 2048 waves = 2 waves/SIMD, zero LDS
  trop_conv_kernel<<<dim3(512), dim3(256), 0, stream>>>(img, kern, out);
}

// Round 3
// 62.672 us; speedup vs baseline: 1.1457x; 1.0144x over previous
//
#include <hip/hip_runtime.h>
#include <math.h>

// Tropical (max-plus) 3x3 conv:
// out[b,o,y,x] = max_{c,dy,dx} imgs[b,c,y+dy-1,x+dx-1] + kernel[o,c,2-dy,2-dx]
// B=8, C=32, O=32, H=W=32, PADDING=1 (-inf), fp32.
//
// R7 design (max-TLP test on the shuffle-free loop):
//  - R6 post-mortem: ~23us kernel residual = ~1700 cy per 32-iter wave
//    loop -> exposed VMEM/SMEM latency at only 2 waves/SIMD, not pipe
//    throughput (models: L1 ~5us, VALU ~3us). R5's occupancy test was
//    confounded by DS-work growth; DS is gone now, so test occupancy
//    cleanly.
//  - Split C four ways across the block: 512 threads = 4 c-groups x 128,
//    each wave does 8 c-iters. Grid 8b x 32o x 4yq = 1024 blocks
//    -> 4 blocks/CU -> 32 waves/CU = 8 waves/SIMD (max occupancy).
//    __launch_bounds__(512,8) caps VGPR at 64 (body needs ~50).
//  - readfirstlane(tid>>7) keeps the weight base PROVABLY wave-uniform
//    (plain tid>>7 defeats uniformity analysis -> weights would demote
//    from s_load to per-lane VMEM).
//  - Hot loop unchanged from R6: 3 coalesced dwordx4 row loads per iter,
//    cndmask x-remap, zero DS. LDS (3KB) only in the final 4-way
//    cross-group max reduction.

constexpr int B = 8, C = 32, O = 32, H = 32, W = 32;
constexpr int HW = H * W;

typedef float f4 __attribute__((ext_vector_type(4)));

__device__ __forceinline__ float f3(float a, float b, float c) {
  return fmaxf(fmaxf(a, b), c);  // -> v_max3_f32
}

// 16B load with only 4B alignment guaranteed (xb may be odd).
__device__ __forceinline__ f4 ld4u(const float* p) {
  f4 q;
  __builtin_memcpy(&q, p, sizeof(q));
  return q;
}

__global__ __launch_bounds__(512, 8) void trop_conv_kernel(
    const float* __restrict__ img, const float* __restrict__ kern,
    float* __restrict__ out) {
  __shared__ float red[3 * 128 * 2];  // cross-group reduction buffer

  const int tid = threadIdx.x;
  const int blk = blockIdx.x;
  const int yq = blk & 3;           // y-quarter (8 rows)
  const int o = (blk >> 2) & 31;    // output channel
  const int b = blk >> 7;

  const int lid = tid & 127;
  // wave-uniform c-group 0..3 (readfirstlane keeps it in an SGPR so the
  // weight loads below stay s_load)
  const int cg = __builtin_amdgcn_readfirstlane(tid >> 7);

  const int seg = lid & 15;         // x-segment: 2 px per lane
  const int x0 = seg * 2;
  const int r = lid >> 4;           // 0..7
  const int y = yq * 8 + r;

  // clamped load base: q covers img columns xb..xb+3
  int xb = x0 - 1;
  xb = xb < 0 ? 0 : xb;
  xb = xb > 28 ? 28 : xb;
  int ym = y - 1; ym = ym < 0 ? 0 : ym;
  int yp = y + 1; yp = yp > 31 ? 31 : yp;
  const int off0 = ym * W + xb;
  const int off1 = y * W + xb;
  const int off2 = yp * W + xb;

  const bool top = (y == 0);
  const bool bot = (y == 31);
  const bool xz = (x0 == 0);    // xb == x0   -> q = x0..x0+3
  const bool xe = (x0 == 30);   // xb == x0-2 -> q = x0-2..x0+1
  const float NEG = -__builtin_huge_valf();

  const float* icb = img + b * C * HW + cg * 8 * HW;
  const float* kc = kern + o * 288 + cg * 8 * 9;

  float acc0 = NEG, acc1 = NEG;

#pragma unroll 2
  for (int i = 0; i < 8; ++i) {
    const float* ic = icb + i * HW;
    const float* kp = kc + i * 9;
    // wave-uniform weight loads (s_load); w[t] = kern[o][c][t/3][t%3]
    const float w0 = kp[0], w1 = kp[1], w2 = kp[2], w3 = kp[3], w4 = kp[4],
                w5 = kp[5], w6 = kp[6], w7 = kp[7], w8 = kp[8];

    const f4 q0 = ld4u(ic + off0);  // row y-1
    const f4 q1 = ld4u(ic + off1);  // row y
    const f4 q2 = ld4u(ic + off2);  // row y+1

    // remap to (x0-1, x0, x0+1, x0+2), edges -> NEG
    const float am = xz ? NEG : (xe ? q0.y : q0.x);
    const float a0 = xe ? q0.z : (xz ? q0.x : q0.y);
    const float a1 = xe ? q0.w : (xz ? q0.y : q0.z);
    const float a2 = xe ? NEG : (xz ? q0.z : q0.w);

    const float bm = xz ? NEG : (xe ? q1.y : q1.x);
    const float b0 = xe ? q1.z : (xz ? q1.x : q1.y);
    const float b1 = xe ? q1.w : (xz ? q1.y : q1.z);
    const float b2 = xe ? NEG : (xz ? q1.z : q1.w);

    const float cm = xz ? NEG : (xe ? q2.y : q2.x);
    const float c0 = xe ? q2.z : (xz ? q2.x : q2.y);
    const float c1 = xe ? q2.w : (xz ? q2.y : q2.z);
    const float c2 = xe ? NEG : (xz ? q2.z : q2.w);

    // weight slot s = 8 - 3*dy - dx; rows (y-1, y, y+1) = dy (0,1,2)
    float t0a = f3(am + w8, a0 + w7, a1 + w6);   // out x0,   row y-1
    float t1a = f3(a0 + w8, a1 + w7, a2 + w6);   // out x0+1, row y-1
    t0a = top ? NEG : t0a;
    t1a = top ? NEG : t1a;

    const float t0b = f3(bm + w5, b0 + w4, b1 + w3);  // row y
    const float t1b = f3(b0 + w5, b1 + w4, b2 + w3);

    float t0c = f3(cm + w2, c0 + w1, c1 + w0);   // row y+1
    float t1c = f3(c0 + w2, c1 + w1, c2 + w0);
    t0c = bot ? NEG : t0c;
    t1c = bot ? NEG : t1c;

    acc0 = fmaxf(acc0, f3(t0a, t0b, t0c));
    acc1 = fmaxf(acc1, f3(t1a, t1b, t1c));
  }

  // ---- 4-way cross-group max reduction (LDS, epilogue only) ----
  if (cg > 0) {
    red[(cg - 1) * 256 + lid * 2] = acc0;
    red[(cg - 1) * 256 + lid * 2 + 1] = acc1;
  }
  __syncthreads();
  if (cg == 0) {
    acc0 = fmaxf(fmaxf(acc0, red[lid * 2]),
                 fmaxf(red[256 + lid * 2], red[512 + lid * 2]));
    acc1 = fmaxf(fmaxf(acc1, red[lid * 2 + 1]),
                 fmaxf(red[256 + lid * 2 + 1], red[512 + lid * 2 + 1]));
    float2 res = make_float2(acc0, acc1);
    *reinterpret_cast<float2*>(&out[((b * O + o) * H + y) * W + x0]) = res;
  }
}

extern "C" void kernel_launch(void* const* d_in, const int* in_sizes, int n_in,
                              void* d_out, int out_size, void* d_ws, size_t ws_size,
                              hipStream_t stream) {
  const float* img = (const float*)d_in[0];
  const float* kern = (const float*)d_in[1];
  float* out = (float*)d_out;
  // grid: b(8) x o(32) x y-quarter(4) = 1024 blocks of 512 threads
  //       -> 4 blocks/CU, 32 waves/CU = 8 waves/SIMD (hardware max)
  trop_conv_kernel<<<dim3(1024), dim3(512), 0, stream>>>(img, kern, out);
}